// Round 3
// baseline (253.337 us; speedup 1.0000x reference)
//
#include <hip/hip_runtime.h>
#include <math.h>

#define TT 2048
#define W 10

typedef short bf16x8 __attribute__((ext_vector_type(8)));
typedef float f32x4 __attribute__((ext_vector_type(4)));

#define MFMA16(a, b, c) __builtin_amdgcn_mfma_f32_16x16x32_bf16((a), (b), (c), 0, 0, 0)

// Round-to-nearest-even hi/lo bf16 split: hi = RNE(v), r = v - hi (exact,
// Sterbenz), lo = RNE(r). |v - hi - lo| <= 2^-16 |v|, unbiased.
__device__ __forceinline__ unsigned short rneBf16(float v) {
  unsigned int u = __float_as_uint(v);
  u += 0x7FFFu + ((u >> 16) & 1u);
  return (unsigned short)(u >> 16);
}
__device__ __forceinline__ void splitRne(float v, unsigned short& hi,
                                         unsigned short& lo) {
  hi = rneBf16(v);
  float r = v - __uint_as_float((unsigned int)hi << 16);
  lo = rneBf16(r);
}

// Wt ushort layout (per array H/L), transposed [h][k]:
//   W1 @0      [64][32]  : k<5   -> p1 row k
//   W2 @2048   [64][32]  : k<30  -> p2 row k
//   W3 @4096   [64][160] : k<155 -> p3 row k
//   W4 @14336  [64][512] : k<155 -> p4 row k; [155,160) zero;
//     [160,485): kap=k-160, c=kap/25, m=kap%25, j=(m+c)%25 ->
//                p4[155+m*25+j] + (c>0)*p4[155+j*25+m]   (symmetric fold)
//     [485,512) zero.
#define OFF_W2 2048
#define OFF_W3 4096
#define OFF_W4 14336
#define WT_TOTAL 47104

// ============== Kernel 1: fused [wprep | prep+gate] ==============
__global__ __launch_bounds__(256) void pre_kernel(
    const float* __restrict__ F,
    const float* __restrict__ hw1, const float* __restrict__ hb1,
    const float* __restrict__ hw2, const float* __restrict__ hb2,
    const float* __restrict__ hw3, const float* __restrict__ hb3,
    const float* __restrict__ gw1, const float* __restrict__ gb1,
    const float* __restrict__ gw2, const float* __restrict__ gb2,
    const float* __restrict__ p1, const float* __restrict__ p2,
    const float* __restrict__ p3, const float* __restrict__ p4,
    unsigned short* __restrict__ WtH, unsigned short* __restrict__ WtL,
    float* __restrict__ gate) {
  const int bid = blockIdx.x;
  const int tid = threadIdx.x;
  if (bid >= 256) {
    int g = (bid - 256) * 256 + tid;
    float v;
    if (g < 2048) {
      int h = g >> 5, k = g & 31;
      v = (k < 5) ? p1[k * 64 + h] : 0.f;
    } else if (g < 4096) {
      int loc = g - 2048, h = loc >> 5, k = loc & 31;
      v = (k < 30) ? p2[k * 64 + h] : 0.f;
    } else if (g < 14336) {
      int loc = g - 4096, h = loc / 160, k = loc - h * 160;
      v = (k < 155) ? p3[k * 64 + h] : 0.f;
    } else {
      int loc = g - 14336, h = loc >> 9, k = loc & 511;
      if (k < 155) {
        v = p4[k * 64 + h];
      } else if (k >= 160 && k < 485) {
        int kap = k - 160;
        int c = kap / 25, mm = kap - c * 25;
        int jj = mm + c;
        if (jj >= 25) jj -= 25;
        v = p4[(155 + mm * 25 + jj) * 64 + h];
        if (c > 0) v += p4[(155 + jj * 25 + mm) * 64 + h];
      } else {
        v = 0.f;
      }
    }
    unsigned short hi, lo;
    splitRne(v, hi, lo);
    WtH[g] = hi;
    WtL[g] = lo;
    return;
  }
  // ---- gate block: row b, positions [t0, t0+256) ----
  __shared__ float sRet[TT];
  __shared__ float sCum[TT];
  __shared__ float sPart[256];
  const int b = bid >> 3;
  const int t0 = (bid & 7) << 8;
  const float* fb = F + (size_t)b * TT * 5;
#pragma unroll
  for (int u = 0; u < 8; ++u) {
    int t = u * 256 + tid;
    sRet[t] = (t > 0) ? (fb[t * 5] - fb[(t - 1) * 5]) : 0.f;
  }
  __syncthreads();
  float loc8[8], run = 0.f;
#pragma unroll
  for (int u = 0; u < 8; ++u) {
    run += fabsf(sRet[tid * 8 + u]);
    loc8[u] = run;
  }
  sPart[tid] = run;
  __syncthreads();
  for (int off = 1; off < 256; off <<= 1) {
    float v = (tid >= off) ? sPart[tid - off] : 0.f;
    __syncthreads();
    sPart[tid] += v;
    __syncthreads();
  }
  float excl = sPart[tid] - run;
#pragma unroll
  for (int u = 0; u < 8; ++u) sCum[tid * 8 + u] = excl + loc8[u];
  __syncthreads();
  // ---- gate MLP at t = t0 + tid ----
  const int t = t0 + tid;
  const float vv = sCum[t] / ((float)(t + 1) + 1e-8f);
  const int start = (t >= W) ? (t - W) : 0;
  float r[W];
#pragma unroll
  for (int u = 0; u < W; ++u) r[u] = sRet[start + u];
  float h1v[32];
#pragma unroll
  for (int j = 0; j < 32; ++j) {
    float a = hb1[j];
#pragma unroll
    for (int u = 0; u < W; ++u) a = fmaf(r[u], hw1[u * 32 + j], a);
    h1v[j] = fmaxf(a, 0.f);
  }
  float hs = hb3[0];
#pragma unroll
  for (int j = 0; j < 32; ++j) {
    float a = hb2[j];
#pragma unroll
    for (int u = 0; u < 32; ++u) a = fmaf(h1v[u], hw2[u * 32 + j], a);
    hs = fmaf(fmaxf(a, 0.f), hw3[j], hs);
  }
  const float H = 0.5f / (1.f + expf(-hs));
  float l0 = gb2[0], l1 = gb2[1], l2 = gb2[2], l3 = gb2[3];
#pragma unroll
  for (int j = 0; j < 32; ++j) {
    float z = fmaxf(fmaf(H, gw1[j], fmaf(vv, gw1[32 + j], gb1[j])), 0.f);
    l0 = fmaf(z, gw2[j * 4 + 0], l0);
    l1 = fmaf(z, gw2[j * 4 + 1], l1);
    l2 = fmaf(z, gw2[j * 4 + 2], l2);
    l3 = fmaf(z, gw2[j * 4 + 3], l3);
  }
  float m = fmaxf(fmaxf(l0, l1), fmaxf(l2, l3));
  float e0 = expf(l0 - m), e1 = expf(l1 - m), e2 = expf(l2 - m),
        e3 = expf(l3 - m);
  float inv = 1.f / (e0 + e1 + e2 + e3);
  ((float4*)gate)[b * TT + t] = make_float4(e0 * inv, e1 * inv, e2 * inv, e3 * inv);
}

// Per-thread signature core for window of position p (local group index).
// sRaw rows lr correspond to global rows t0-10+lr; Dw[r] = row(p+r+1)-row(p+r),
// valid iff global q = t0+p+r-10 >= 0.  GUARD path only for t0==0 blocks
// (valid <=> p+r >= 10).  Register revcumsum: sfi = S[r,fi]; a = A-cumsum;
// aa (pre-update a) = RA[r,e,f]; l3a[i] = sum_r Dw[r,i]*RA[r] = l3f[i,e,f].
template <bool GUARD>
static __device__ __forceinline__ void sigCore(const float* sR, int p, int e,
                                               int fi, float* l3a, float& aout,
                                               float& sout) {
  int b10 = (p + 10) * 5;
  float h0 = sR[b10 + 0], h1 = sR[b10 + 1], h2 = sR[b10 + 2], h3 = sR[b10 + 3],
        h4 = sR[b10 + 4];
  float hiE = sR[b10 + e], hiF = sR[b10 + fi];
  float a = 0.f, sfi = 0.f;
  float l0 = 0.f, l1 = 0.f, l2 = 0.f, l3 = 0.f, l4 = 0.f;
#pragma unroll
  for (int r = 9; r >= 0; --r) {
    const int base = (p + r) * 5;
    float n0 = sR[base + 0], n1 = sR[base + 1], n2 = sR[base + 2],
          n3 = sR[base + 3], n4 = sR[base + 4];
    float nE = sR[base + e], nF = sR[base + fi];
    float d0 = h0 - n0, d1 = h1 - n1, d2 = h2 - n2, d3 = h3 - n3, d4 = h4 - n4;
    float dE = hiE - nE, dF = hiF - nF;
    if (GUARD) {
      float vm = ((p + r) >= 10) ? 1.f : 0.f;
      d0 *= vm; d1 *= vm; d2 *= vm; d3 *= vm; d4 *= vm; dE *= vm; dF *= vm;
    }
    sfi += dF;
    float aa = a;
    l0 = fmaf(d0, aa, l0);
    l1 = fmaf(d1, aa, l1);
    l2 = fmaf(d2, aa, l2);
    l3 = fmaf(d3, aa, l3);
    l4 = fmaf(d4, aa, l4);
    a = fmaf(dE, sfi, a);
    h0 = n0; h1 = n1; h2 = n2; h3 = n3; h4 = n4; hiE = nE; hiF = nF;
  }
  l3a[0] = l0; l3a[1] = l1; l3a[2] = l2; l3a[3] = l3; l3a[4] = l4;
  aout = a;
  sout = sfi;
}

// ============== Kernel 2: phi (symmetric l4, bf16 hi/lo) + MFMA + head ========
// phi K = 512: l1[0,5) l2[5,30) l3[30,155) pad[155,160) l4sym[160,485) pad[485,512)
// Row stride 520 ushorts (1040 B, 16B-aligned).
// LDS: phiH+phiL 33,280 B + sRaw 528 B = 33.8 KB.
// Epilogue overlays: sSigA/sSigB on phiH, sBn on phiL.
// BARRIER DISCIPLINE: every __syncthreads() is in block-uniform control flow
// (round-0-proven). Divergent branches contain only register math + loads;
// overlay stores happen after a uniform barrier.
__global__ __launch_bounds__(512, 6) void sig_kernel(
    const float* __restrict__ F, const float* __restrict__ gate,
    const unsigned short* __restrict__ WtH, const unsigned short* __restrict__ WtL,
    const float* __restrict__ p1b, const float* __restrict__ p2b,
    const float* __restrict__ p3b, const float* __restrict__ p4b,
    const float* __restrict__ w1, const float* __restrict__ b1,
    const float* __restrict__ gam, const float* __restrict__ bet,
    const float* __restrict__ rmean, const float* __restrict__ rvar,
    const float* __restrict__ w2, const float* __restrict__ b2,
    const float* __restrict__ w3, const float* __restrict__ b3,
    float* __restrict__ out) {
  __shared__ __align__(16) unsigned short phiH[16][520];
  __shared__ __align__(16) unsigned short phiL[16][520];
  __shared__ float sRaw[132];

  const int tid = threadIdx.x;
  const int posBase = blockIdx.x * 16;
  const int t0 = posBase & (TT - 1);

  // ---- P0: zero phi pads + stage F window (26 rows x 5, contiguous) ----
  {
    int p = tid >> 5, mm = tid & 31;
    int kk = (mm < 5) ? (155 + mm) : (480 + mm);  // [155,160) and [485,512)
    phiH[p][kk] = 0;
    phiL[p][kk] = 0;
  }
  if (tid < 130) {
    const float* fb = F + (size_t)(posBase - t0) * 5;
    int idx = (t0 - W) * 5 + tid;
    sRaw[tid] = (idx >= 0) ? fb[idx] : 0.f;
  }
  __syncthreads();

  // ---- P1: fused l1/l2/l3 (register revcumsum) + l4 (in-wave shuffle) ----
  const int pgrp = tid >> 5;  // position group, half-wave aligned
  const int m = tid & 31;     // 25 active lanes per group
  float l2v = 0.f;
  if (m < 25) {
    const int e = m / 5;
    const int fi = m - e * 5;
    float l3a[5], a, sfi;
    if (t0 != 0)
      sigCore<false>(sRaw, pgrp, e, fi, l3a, a, sfi);
    else
      sigCore<true>(sRaw, pgrp, e, fi, l3a, a, sfi);
    l2v = a;
    unsigned short hi, lo;
    if (m < 5) {
      splitRne(sfi, hi, lo);  // lvl1 = S[0, m]
      phiH[pgrp][m] = hi;
      phiL[pgrp][m] = lo;
    }
    splitRne(a, hi, lo);  // l2f[m]
    phiH[pgrp][5 + m] = hi;
    phiL[pgrp][5 + m] = lo;
#pragma unroll
    for (int i = 0; i < 5; ++i) {  // l3f[i*25+m]
      splitRne(l3a[i], hi, lo);
      phiH[pgrp][30 + i * 25 + m] = hi;
      phiL[pgrp][30 + i * 25 + m] = lo;
    }
  }
  // l4 symmetric products: pair {m, (m+c)%25}, c=0..12 -> phi k = 160+c*25+m
  const int laneBase = tid & 32;
#pragma unroll
  for (int c = 0; c < 13; ++c) {
    int j = m + c;
    if (j >= 25) j -= 25;
    float other = __shfl(l2v, laneBase + j, 64);
    if (m < 25) {
      unsigned short hi, lo;
      splitRne(l2v * other, hi, lo);
      phiH[pgrp][160 + c * 25 + m] = hi;
      phiL[pgrp][160 + c * 25 + m] = lo;
    }
  }
  __syncthreads();

  // ---- P2: MFMA. wave = (h-tile ht, K-group kg). No barriers inside
  // branches: results are folded into registers, stored after uniform sync.
  const int lane = tid & 63;
  const int wv = tid >> 6;  // 0..7
  const int ht = wv & 3, kg = wv >> 2;
  const int col = lane & 15, quad = lane >> 4;
  const int hw = ht * 16;
  const int arow = hw + col;

  const unsigned short* bHp = &phiH[col][quad * 8];
  const unsigned short* bLp = &phiL[col][quad * 8];
  const unsigned short* a4H = WtH + OFF_W4 + arow * 512 + quad * 8;
  const unsigned short* a4L = WtL + OFF_W4 + arow * 512 + quad * 8;

  const int pos = posBase + col;
  const int t = pos & (TT - 1);
  float4 g = ((const float4*)gate)[pos];  // issued early, hides under MFMAs
  const float g0 = g.x;
  const float g1 = (t >= 1) ? g.y : 0.f;
  const float g2 = (t >= 2) ? g.z : 0.f;
  const float g3 = (t >= 3) ? g.w : 0.f;

  f32x4 res;       // kg0: g3*a4 + gated bias;  kg1: gate-combined partials
  if (kg == 0) {   // W4 slices 0..11: 36 MFMAs
    f32x4 t4a = {0.f, 0.f, 0.f, 0.f}, t4b = {0.f, 0.f, 0.f, 0.f};
    for (int s = 0; s < 12; ++s) {
      bf16x8 bh = *(const bf16x8*)(bHp + s * 32);
      bf16x8 bl = *(const bf16x8*)(bLp + s * 32);
      bf16x8 ah = *(const bf16x8*)(a4H + s * 32);
      bf16x8 al = *(const bf16x8*)(a4L + s * 32);
      t4a = MFMA16(ah, bh, t4a);
      t4b = MFMA16(ah, bl, t4b);
      t4b = MFMA16(al, bh, t4b);
    }
    f32x4 a4 = t4a + t4b;
    const int hq = hw + quad * 4;
    f32x4 b1v = *(const f32x4*)(p1b + hq);
    f32x4 b2v = *(const f32x4*)(p2b + hq);
    f32x4 b3v = *(const f32x4*)(p3b + hq);
    f32x4 b4v = *(const f32x4*)(p4b + hq);
#pragma unroll
    for (int r = 0; r < 4; ++r)
      res[r] = g3 * a4[r] + g0 * b1v[r] + g1 * b2v[r] + g2 * b3v[r] + g3 * b4v[r];
  } else {  // W4 slices 12..15 + W3 + W2 + W1: 33 MFMAs
    f32x4 t4a = {0.f, 0.f, 0.f, 0.f}, t4b = {0.f, 0.f, 0.f, 0.f};
    for (int s = 12; s < 16; ++s) {
      bf16x8 bh = *(const bf16x8*)(bHp + s * 32);
      bf16x8 bl = *(const bf16x8*)(bLp + s * 32);
      bf16x8 ah = *(const bf16x8*)(a4H + s * 32);
      bf16x8 al = *(const bf16x8*)(a4L + s * 32);
      t4a = MFMA16(ah, bh, t4a);
      t4b = MFMA16(ah, bl, t4b);
      t4b = MFMA16(al, bh, t4b);
    }
    f32x4 a4 = t4a + t4b;
    const unsigned short* a3H = WtH + OFF_W3 + arow * 160 + quad * 8;
    const unsigned short* a3L = WtL + OFF_W3 + arow * 160 + quad * 8;
    f32x4 t3a = {0.f, 0.f, 0.f, 0.f}, t3b = {0.f, 0.f, 0.f, 0.f};
    for (int s = 0; s < 5; ++s) {
      bf16x8 bh = *(const bf16x8*)(bHp + s * 32);
      bf16x8 bl = *(const bf16x8*)(bLp + s * 32);
      bf16x8 ch = *(const bf16x8*)(a3H + s * 32);
      bf16x8 cl = *(const bf16x8*)(a3L + s * 32);
      t3a = MFMA16(ch, bh, t3a);
      t3b = MFMA16(ch, bl, t3b);
      t3b = MFMA16(cl, bh, t3b);
    }
    f32x4 a3 = t3a + t3b;
    bf16x8 bh0 = *(const bf16x8*)(bHp);
    bf16x8 bl0 = *(const bf16x8*)(bLp);
    f32x4 acc2 = {0.f, 0.f, 0.f, 0.f}, acc1 = {0.f, 0.f, 0.f, 0.f};
    const unsigned short* a2H = WtH + OFF_W2 + arow * 32 + quad * 8;
    const unsigned short* a2L = WtL + OFF_W2 + arow * 32 + quad * 8;
    bf16x8 dh = *(const bf16x8*)a2H;
    bf16x8 dl = *(const bf16x8*)a2L;
    acc2 = MFMA16(dh, bh0, acc2);
    acc2 = MFMA16(dh, bl0, acc2);
    acc2 = MFMA16(dl, bh0, acc2);
    const unsigned short* a1H = WtH + arow * 32 + quad * 8;
    const unsigned short* a1L = WtL + arow * 32 + quad * 8;
    bf16x8 eh = *(const bf16x8*)a1H;
    bf16x8 el = *(const bf16x8*)a1L;
    acc1 = MFMA16(eh, bh0, acc1);
    acc1 = MFMA16(eh, bl0, acc1);
    acc1 = MFMA16(el, bh0, acc1);
#pragma unroll
    for (int r = 0; r < 4; ++r)
      res[r] = g0 * acc1[r] + g1 * acc2[r] + g2 * a3[r] + g3 * a4[r];
  }

  __syncthreads();  // UNIFORM: all phi reads complete -> overlays safe

  float* sSigA = (float*)&phiH[0][0];  // [16][66] overlay
  float* sSigB = sSigA + 16 * 66;      // [16][66]
  {
    float* dst = (kg == 0) ? sSigA : sSigB;
    const int hq = hw + quad * 4;
#pragma unroll
    for (int r = 0; r < 4; ++r) dst[col * 66 + hq + r] = res[r];
  }
  __syncthreads();  // UNIFORM

  // ---- Head: h1+BN. wave handles 2 positions, lane = output channel j ----
  {
    const int j = lane;
    const int pA = wv * 2, pB = pA + 1;
    float a0 = b1[j], a1 = a0;
    const float* sA0 = sSigA + pA * 66;
    const float* sB0 = sSigB + pA * 66;
    const float* sA1 = sSigA + pB * 66;
    const float* sB1 = sSigB + pB * 66;
    for (int i = 0; i < 64; ++i) {
      float wt = w1[i * 64 + j];
      a0 = fmaf(sA0[i] + sB0[i], wt, a0);
      a1 = fmaf(sA1[i] + sB1[i], wt, a1);
    }
#pragma unroll
    for (int i = 0; i < 5; ++i) {
      float wt = w1[(64 + i) * 64 + j];
      a0 = fmaf(sRaw[(10 + pA) * 5 + i], wt, a0);
      a1 = fmaf(sRaw[(10 + pB) * 5 + i], wt, a1);
    }
    float sc = gam[j] * rsqrtf(rvar[j] + 1e-5f);
    float rm = rmean[j], be = bet[j];
    float* sBn = (float*)&phiL[0][0];  // [16][64] overlay
    sBn[pA * 64 + j] = fmaf(fmaxf(a0, 0.f) - rm, sc, be);
    sBn[pB * 64 + j] = fmaf(fmaxf(a1, 0.f) - rm, sc, be);
  }
  __syncthreads();  // UNIFORM

  // ---- h2 + output: 512 tasks = 16 pos x 32 k ----
  {
    const float* sBn = (const float*)&phiL[0][0];
    const float b3s = b3[0];
    int p = tid >> 5, k = tid & 31;
    const float* bnp = sBn + p * 64;
    float a = b2[k];
    for (int jj = 0; jj < 64; ++jj) a = fmaf(bnp[jj], w2[jj * 32 + k], a);
    float partial = fmaxf(a, 0.f) * w3[k];
#pragma unroll
    for (int off = 16; off >= 1; off >>= 1) partial += __shfl_xor(partial, off, 32);
    if (k == 0) out[posBase + p] = 1.5f * tanhf(partial + b3s);
  }
}

extern "C" void kernel_launch(void* const* d_in, const int* in_sizes, int n_in,
                              void* d_out, int out_size, void* d_ws, size_t ws_size,
                              hipStream_t stream) {
  const float* F = (const float*)d_in[0];
  const float* hw1 = (const float*)d_in[1];
  const float* hb1 = (const float*)d_in[2];
  const float* hw2 = (const float*)d_in[3];
  const float* hb2 = (const float*)d_in[4];
  const float* hw3 = (const float*)d_in[5];
  const float* hb3 = (const float*)d_in[6];
  const float* gw1 = (const float*)d_in[7];
  const float* gb1 = (const float*)d_in[8];
  const float* gw2 = (const float*)d_in[9];
  const float* gb2 = (const float*)d_in[10];
  const float* p1 = (const float*)d_in[11];
  const float* p1b = (const float*)d_in[12];
  const float* p2 = (const float*)d_in[13];
  const float* p2b = (const float*)d_in[14];
  const float* p3 = (const float*)d_in[15];
  const float* p3b = (const float*)d_in[16];
  const float* p4 = (const float*)d_in[17];
  const float* p4b = (const float*)d_in[18];
  const float* w1 = (const float*)d_in[19];
  const float* b1 = (const float*)d_in[20];
  const float* gam = (const float*)d_in[21];
  const float* bet = (const float*)d_in[22];
  const float* rmean = (const float*)d_in[23];
  const float* rvar = (const float*)d_in[24];
  const float* w2 = (const float*)d_in[25];
  const float* b2 = (const float*)d_in[26];
  const float* w3 = (const float*)d_in[27];
  const float* b3 = (const float*)d_in[28];

  float* ws = (float*)d_ws;
  float* gate = ws;                                      // 262144 floats
  unsigned short* WtH = (unsigned short*)(ws + 262144);  // 47104 ushorts
  unsigned short* WtL = WtH + WT_TOTAL;                  // 47104 ushorts
  float* out = (float*)d_out;                            // 65536 floats

  // 256 gate blocks + 184 repack blocks (47104 / 256)
  pre_kernel<<<440, 256, 0, stream>>>(F, hw1, hb1, hw2, hb2, hw3, hb3, gw1,
                                      gb1, gw2, gb2, p1, p2, p3, p4, WtH, WtL,
                                      gate);
  sig_kernel<<<4096, 512, 0, stream>>>(F, gate, WtH, WtL, p1b, p2b, p3b, p4b,
                                       w1, b1, gam, bet, rmean, rvar, w2, b2,
                                       w3, b3, out);
}